// Round 4
// baseline (42.184 us; speedup 1.0000x reference)
//
#include <hip/hip_runtime.h>
#include <hip/hip_bf16.h>

typedef __attribute__((ext_vector_type(8))) short short8_t;
typedef __attribute__((ext_vector_type(4))) short short4_t;
typedef __attribute__((ext_vector_type(4))) float f32x4;

#define S_DIM   1024
#define D_DIM   64
#define BM      64             // rows per block -> 512 blocks, 2/CU
#define KC      64
#define NCHUNK  (S_DIM / KC)   // 16
#define BSTRIDE 72             // u16 per row of B^T chunk (144B, bank-spread)
#define THREADS 512

__device__ __forceinline__ ushort f2bf(float f) {
    __hip_bfloat16 h = __float2bfloat16(f);   // RTNE
    return __builtin_bit_cast(ushort, h);
}

// Publish LDS writes only; global loads stay in flight across the barrier.
#define SYNC() do { \
    __builtin_amdgcn_sched_barrier(0); \
    asm volatile("s_waitcnt lgkmcnt(0)"); \
    __builtin_amdgcn_s_barrier(); \
    __builtin_amdgcn_sched_barrier(0); \
} while (0)

__global__ __launch_bounds__(THREADS, 4)   // VGPR<=128 -> 2 blocks/CU
void gemm_sm_kernel(const float* __restrict__ x1,
                    const float* __restrict__ x2,
                    float* __restrict__ out) {
    // Only B goes through LDS now (transpose staging). A streams global->reg.
    __shared__ ushort lds_b[2][D_DIM * BSTRIDE];

    const int tid = threadIdx.x;
    const int bid = blockIdx.x;
    // XCD-aware: bid&7 = XCD; each XCD owns 4 batches (B panels L2-resident)
    const int xcd = bid & 7;
    const int q   = bid >> 3;              // 0..63
    const int batch   = xcd * 4 + (q & 3); // 0..31
    const int rowtile = q >> 2;            // 0..15
    const int row0    = rowtile * BM;

    const float* Abase = x1 + (size_t)batch * (S_DIM * S_DIM) + (size_t)row0 * S_DIM;
    const float* Bbase = x2 + (size_t)batch * (S_DIM * D_DIM);
    float*       Cbase = out + (size_t)batch * (S_DIM * D_DIM) + (size_t)row0 * D_DIM;

    const int w = tid >> 6;   // wave 0..7
    const int l = tid & 63;   // lane

    // wave tile: 16 rows x 32 cols (wm 0..3, wn 0..1)
    const int wm = w >> 1, wn = w & 1;
    const int fr = l & 15, fg = l >> 4;

    // ---- A direct-to-reg: lane's fragment row pointer (k-contiguous) ----
    const float* arow = Abase + (size_t)(wm * 16 + fr) * S_DIM + fg * 8;

    // ---- B staging: lane = d, wave picks k-groups ----
    const int bd  = l;
    const int bk0 = w * 4;                 // k-local base (+32 for second half)

    int bidx[2][2];
    #pragma unroll
    for (int nf = 0; nf < 2; ++nf) {
        const int col = wn * 32 + nf * 16 + fr;
        #pragma unroll
        for (int ks = 0; ks < 2; ++ks)
            bidx[nf][ks] = col * BSTRIDE + ks * 32 + fg * 8;
    }

    // 2-deep register prefetch (named -> static indexing)
    float araw0[16], araw1[16];    // [ks*8 + j]
    float breg0[8],  breg1[8];

    auto loadA = [&](int t, float (&A)[16]) {
        #pragma unroll
        for (int ks = 0; ks < 2; ++ks) {
            const float* p = arow + t * KC + ks * 32;
            float4 v0 = *reinterpret_cast<const float4*>(p);
            float4 v1 = *reinterpret_cast<const float4*>(p + 4);
            A[ks * 8 + 0] = v0.x; A[ks * 8 + 1] = v0.y;
            A[ks * 8 + 2] = v0.z; A[ks * 8 + 3] = v0.w;
            A[ks * 8 + 4] = v1.x; A[ks * 8 + 5] = v1.y;
            A[ks * 8 + 6] = v1.z; A[ks * 8 + 7] = v1.w;
        }
    };
    auto loadB = [&](int t, float (&B)[8]) {
        const float* bp = Bbase + (size_t)t * KC * D_DIM + bd;
        #pragma unroll
        for (int i = 0; i < 2; ++i)
            #pragma unroll
            for (int j = 0; j < 4; ++j)
                B[i * 4 + j] = bp[(bk0 + 32 * i + j) * D_DIM];
    };
    auto storeB = [&](ushort* lb, const float (&B)[8]) {
        #pragma unroll
        for (int i = 0; i < 2; ++i) {
            short4_t bv;
            #pragma unroll
            for (int j = 0; j < 4; ++j) bv[j] = (short)f2bf(B[i * 4 + j]);
            *reinterpret_cast<short4_t*>(&lb[bd * BSTRIDE + bk0 + 32 * i]) = bv;
        }
    };

    f32x4 acc[2];
    acc[0] = f32x4{0.f, 0.f, 0.f, 0.f};
    acc[1] = f32x4{0.f, 0.f, 0.f, 0.f};

    auto compute = [&](const float (&A)[16], const ushort* lb) {
        short8_t af[2];
        #pragma unroll
        for (int ks = 0; ks < 2; ++ks)
            #pragma unroll
            for (int j = 0; j < 8; ++j)
                af[ks][j] = (short)f2bf(A[ks * 8 + j]);
        short8_t bf[2][2];
        #pragma unroll
        for (int nf = 0; nf < 2; ++nf)
            #pragma unroll
            for (int ks = 0; ks < 2; ++ks)
                bf[nf][ks] = *reinterpret_cast<const short8_t*>(&lb[bidx[nf][ks]]);
        #pragma unroll
        for (int ks = 0; ks < 2; ++ks)
            #pragma unroll
            for (int nf = 0; nf < 2; ++nf)
                acc[nf] = __builtin_amdgcn_mfma_f32_16x16x32_bf16(
                    af[ks], bf[nf][ks], acc[nf], 0, 0, 0);
    };

    // ---- pipeline: chunk t regs in (t&1 ? *1 : *0); LDS buf = t&1 ----
    loadA(0, araw0); loadB(0, breg0);
    loadA(1, araw1); loadB(1, breg1);
    storeB(&lds_b[0][0], breg0);
    SYNC();

    #pragma unroll 1
    for (int ti = 0; ti < NCHUNK; ti += 2) {
        // even: compute chunk ti from buf0; publish ti+1; issue ti+2
        {
            float afrag[16];
            #pragma unroll
            for (int j = 0; j < 16; ++j) afrag[j] = araw0[j];  // consume before reload
            if (ti + 2 < NCHUNK) { loadA(ti + 2, araw0); loadB(ti + 2, breg0); }
            storeB(&lds_b[1][0], breg1);
            compute(afrag, &lds_b[0][0]);
        }
        SYNC();
        // odd: compute chunk ti+1 from buf1; publish ti+2; issue ti+3
        {
            float afrag[16];
            #pragma unroll
            for (int j = 0; j < 16; ++j) afrag[j] = araw1[j];
            if (ti + 3 < NCHUNK) { loadA(ti + 3, araw1); loadB(ti + 3, breg1); }
            if (ti + 2 < NCHUNK) storeB(&lds_b[0][0], breg0);
            compute(afrag, &lds_b[1][0]);
        }
        SYNC();
    }

    // epilogue: C/D layout col = lane&15, row = (lane>>4)*4 + j  [m89-verified]
    #pragma unroll
    for (int nf = 0; nf < 2; ++nf)
        #pragma unroll
        for (int j = 0; j < 4; ++j) {
            const int r = wm * 16 + fg * 4 + j;
            const int c = wn * 32 + nf * 16 + fr;
            Cbase[(size_t)r * D_DIM + c] = acc[nf][j];
        }
}

extern "C" void kernel_launch(void* const* d_in, const int* in_sizes, int n_in,
                              void* d_out, int out_size, void* d_ws, size_t ws_size,
                              hipStream_t stream) {
    const float* x1 = (const float*)d_in[0];
    const float* x2 = (const float*)d_in[1];
    float* out = (float*)d_out;
    dim3 grid(512), block(THREADS);
    gemm_sm_kernel<<<grid, block, 0, stream>>>(x1, x2, out);
}

// Round 5
// 31.262 us; speedup vs baseline: 1.3494x; 1.3494x over previous
//
#include <hip/hip_runtime.h>
#include <hip/hip_bf16.h>

typedef __attribute__((ext_vector_type(8))) short short8_t;
typedef __attribute__((ext_vector_type(4))) short short4_t;
typedef __attribute__((ext_vector_type(4))) float f32x4;

#define S_DIM   1024
#define D_DIM   64
#define BM      128            // rows per block -> 256 blocks, 1/CU
#define KC      64
#define NCHUNK  (S_DIM / KC)   // 16
#define BSTRIDE 72             // u16 per row of B^T chunk (144B, bank-spread)
#define THREADS 512

__device__ __forceinline__ ushort f2bf(float f) {
    __hip_bfloat16 h = __float2bfloat16(f);   // RTNE
    return __builtin_bit_cast(ushort, h);
}

// Publish LDS writes only; global loads stay in flight across the barrier.
#define SYNC() do { \
    __builtin_amdgcn_sched_barrier(0); \
    asm volatile("s_waitcnt lgkmcnt(0)"); \
    __builtin_amdgcn_s_barrier(); \
    __builtin_amdgcn_sched_barrier(0); \
} while (0)

__global__ __launch_bounds__(THREADS, 1)
void gemm_sm_kernel(const float* __restrict__ x1,
                    const float* __restrict__ x2,
                    float* __restrict__ out) {
    // Only B goes through LDS (transpose staging). A streams global->reg,
    // each wave owns a DISTINCT 16-row strip (no duplicate A loads).
    __shared__ ushort lds_b[2][D_DIM * BSTRIDE];

    const int tid = threadIdx.x;
    const int bid = blockIdx.x;
    // XCD-aware: 8 row-tiles of one (b,h) share an XCD's L2 (B panel reuse)
    const int batch   = (bid & 7) * 4 + (bid >> 6);   // 0..31
    const int rowtile = (bid >> 3) & 7;               // 0..7
    const int row0    = rowtile * BM;

    const float* Abase = x1 + (size_t)batch * (S_DIM * S_DIM) + (size_t)row0 * S_DIM;
    const float* Bbase = x2 + (size_t)batch * (S_DIM * D_DIM);
    float*       Cbase = out + (size_t)batch * (S_DIM * D_DIM) + (size_t)row0 * D_DIM;

    const int w = tid >> 6;   // wave 0..7 -> owns rows w*16 .. w*16+15
    const int l = tid & 63;   // lane
    const int fr = l & 15, fg = l >> 4;

    // ---- A direct-to-reg: lane's fragment row (k-contiguous 8 floats / ks) ----
    const float* arow = Abase + (size_t)(w * 16 + fr) * S_DIM + fg * 8;

    // ---- B staging: lane = d, wave picks k-groups (identical to R2) ----
    const int bd  = l;
    const int bk0 = w * 4;                 // k-local base (+32 for second half)

    // B fragment indices: each wave reads all 64 cols (4 nf fragments)
    int bidx[4][2];
    #pragma unroll
    for (int nf = 0; nf < 4; ++nf) {
        const int col = nf * 16 + fr;
        #pragma unroll
        for (int ks = 0; ks < 2; ++ks)
            bidx[nf][ks] = col * BSTRIDE + ks * 32 + fg * 8;
    }

    // 2-deep register prefetch (named -> static indexing)
    float a0[16], a1[16], b0[8], b1[8];

    auto loadA = [&](int t, float (&A)[16]) {
        #pragma unroll
        for (int ks = 0; ks < 2; ++ks) {
            const float* p = arow + t * KC + ks * 32;
            float4 v0 = *reinterpret_cast<const float4*>(p);
            float4 v1 = *reinterpret_cast<const float4*>(p + 4);
            A[ks * 8 + 0] = v0.x; A[ks * 8 + 1] = v0.y;
            A[ks * 8 + 2] = v0.z; A[ks * 8 + 3] = v0.w;
            A[ks * 8 + 4] = v1.x; A[ks * 8 + 5] = v1.y;
            A[ks * 8 + 6] = v1.z; A[ks * 8 + 7] = v1.w;
        }
    };
    auto loadB = [&](int t, float (&B)[8]) {
        const float* bp = Bbase + (size_t)t * KC * D_DIM + bd;
        #pragma unroll
        for (int i = 0; i < 2; ++i)
            #pragma unroll
            for (int j = 0; j < 4; ++j)
                B[i * 4 + j] = bp[(bk0 + 32 * i + j) * D_DIM];
    };
    auto storeB = [&](ushort* lb, const float (&B)[8]) {
        #pragma unroll
        for (int i = 0; i < 2; ++i) {
            short4_t bv;
            #pragma unroll
            for (int j = 0; j < 4; ++j) bv[j] = (short)f2bf(B[i * 4 + j]);
            *reinterpret_cast<short4_t*>(&lb[bd * BSTRIDE + bk0 + 32 * i]) = bv;
        }
    };

    f32x4 acc[4];
    #pragma unroll
    for (int nf = 0; nf < 4; ++nf) acc[nf] = f32x4{0.f, 0.f, 0.f, 0.f};

    // build af (consumes A regs -> they may be reloaded afterwards)
    auto buildAF = [&](const float (&A)[16], short8_t (&af)[2]) {
        #pragma unroll
        for (int ks = 0; ks < 2; ++ks)
            #pragma unroll
            for (int j = 0; j < 8; ++j)
                af[ks][j] = (short)f2bf(A[ks * 8 + j]);
    };
    auto computeMFMA = [&](const short8_t (&af)[2], const ushort* lb) {
        #pragma unroll
        for (int nf = 0; nf < 4; ++nf) {
            #pragma unroll
            for (int ks = 0; ks < 2; ++ks) {
                short8_t bf = *reinterpret_cast<const short8_t*>(&lb[bidx[nf][ks]]);
                acc[nf] = __builtin_amdgcn_mfma_f32_16x16x32_bf16(
                    af[ks], bf, acc[nf], 0, 0, 0);
            }
        }
    };

    // ---- pipeline: chunk t regs in (t&1 ? *1 : *0); B LDS buf = t&1 ----
    loadA(0, a0); loadB(0, b0);
    loadA(1, a1); loadB(1, b1);
    storeB(&lds_b[0][0], b0);
    SYNC();

    #pragma unroll 1
    for (int ti = 0; ti < NCHUNK; ti += 2) {
        // even: consume a0 -> af (waits A(ti) via counted vmcnt), reload a0/b0,
        //       publish B(ti+1) -> lds1, compute chunk ti from lds0
        {
            short8_t af[2];
            buildAF(a0, af);
            if (ti + 2 < NCHUNK) { loadA(ti + 2, a0); loadB(ti + 2, b0); }
            storeB(&lds_b[1][0], b1);
            computeMFMA(af, &lds_b[0][0]);
        }
        SYNC();
        // odd: consume a1, reload a1/b1, publish B(ti+2) -> lds0, compute from lds1
        {
            short8_t af[2];
            buildAF(a1, af);
            if (ti + 3 < NCHUNK) { loadA(ti + 3, a1); loadB(ti + 3, b1); }
            if (ti + 2 < NCHUNK) storeB(&lds_b[0][0], b0);
            computeMFMA(af, &lds_b[1][0]);
        }
        SYNC();
    }

    // epilogue: C/D layout col = lane&15, row = (lane>>4)*4 + j  [m89-verified]
    #pragma unroll
    for (int nf = 0; nf < 4; ++nf)
        #pragma unroll
        for (int j = 0; j < 4; ++j) {
            const int r = w * 16 + fg * 4 + j;
            const int c = nf * 16 + fr;
            Cbase[(size_t)r * D_DIM + c] = acc[nf][j];
        }
}

extern "C" void kernel_launch(void* const* d_in, const int* in_sizes, int n_in,
                              void* d_out, int out_size, void* d_ws, size_t ws_size,
                              hipStream_t stream) {
    const float* x1 = (const float*)d_in[0];
    const float* x2 = (const float*)d_in[1];
    float* out = (float*)d_out;
    dim3 grid(256), block(THREADS);
    gemm_sm_kernel<<<grid, block, 0, stream>>>(x1, x2, out);
}

// Round 6
// 27.746 us; speedup vs baseline: 1.5203x; 1.1267x over previous
//
#include <hip/hip_runtime.h>
#include <hip/hip_bf16.h>

typedef __attribute__((ext_vector_type(8))) short short8_t;
typedef __attribute__((ext_vector_type(4))) short short4_t;
typedef __attribute__((ext_vector_type(4))) float f32x4;

#define S_DIM   1024
#define D_DIM   64
#define BM      128            // rows per block -> 256 blocks, 1/CU
#define KC      128            // k per chunk -> 512B bursts per row, 8 chunks
#define NCHUNK  (S_DIM / KC)   // 8
#define BSTRIDE 136            // u16 per row of B^T chunk (272B, bank-spread)
#define THREADS 512

__device__ __forceinline__ ushort f2bf(float f) {
    __hip_bfloat16 h = __float2bfloat16(f);   // RTNE
    return __builtin_bit_cast(ushort, h);
}

// Publish LDS writes only; global loads stay in flight across the barrier.
#define SYNC() do { \
    __builtin_amdgcn_sched_barrier(0); \
    asm volatile("s_waitcnt lgkmcnt(0)"); \
    __builtin_amdgcn_s_barrier(); \
    __builtin_amdgcn_sched_barrier(0); \
} while (0)

__global__ __launch_bounds__(THREADS, 1)
void gemm_sm_kernel(const float* __restrict__ x1,
                    const float* __restrict__ x2,
                    float* __restrict__ out) {
    __shared__ ushort lds_a[2][BM * KC];          // 2 x 32 KB, XOR-swizzled
    __shared__ ushort lds_b[2][D_DIM * BSTRIDE];  // 2 x 17 KB, pad-136

    const int tid = threadIdx.x;
    const int bid = blockIdx.x;
    // XCD-aware: 8 row-tiles of one (b,h) share an XCD's L2 (B panel reuse)
    const int batch   = (bid & 7) * 4 + (bid >> 6);   // 0..31
    const int rowtile = (bid >> 3) & 7;               // 0..7
    const int row0    = rowtile * BM;

    const float* Abase = x1 + (size_t)batch * (S_DIM * S_DIM) + (size_t)row0 * S_DIM;
    const float* Bbase = x2 + (size_t)batch * (S_DIM * D_DIM);
    float*       Cbase = out + (size_t)batch * (S_DIM * D_DIM) + (size_t)row0 * D_DIM;

    const int w = tid >> 6;   // wave 0..7 -> owns rows w*16..w*16+15
    const int l = tid & 63;
    const int fr = l & 15, fg = l >> 4;

    // ---- A staging, linear-burst map: round i covers bytes [i*8K, i*8K+8K)
    // of the chunk's (128 rows x 512B) strided region. Per wave-instruction:
    // 2 rows x 512B CONTIGUOUS bursts (vs 64x16B scatter before).
    const int arow  = tid >> 5;          // row 0..15 (+ i*16 per round)
    const int acol4 = (tid & 31) * 4;    // float offset within 512B window
    const float* aptr = Abase + (size_t)arow * S_DIM + acol4;
    const int aw_u16 = (arow * KC + acol4) ^ ((arow & 7) << 3);  // + i*16*KC

    // ---- B staging: lane = d, wave picks k-groups ----
    const int bd  = l;
    const int bk0 = w * 4;               // k-local base (+i*32)

    // ---- fragment indices ----
    int aidx[4];
    {
        const int row = w * 16 + fr;
        #pragma unroll
        for (int ks = 0; ks < 4; ++ks)
            aidx[ks] = (row * KC + ks * 32 + fg * 8) ^ ((row & 7) << 3);
    }
    int bbase[4];
    #pragma unroll
    for (int nf = 0; nf < 4; ++nf)
        bbase[nf] = (nf * 16 + fr) * BSTRIDE + fg * 8;   // + ks*32 folds to imm

    // 1-deep register prefetch
    float4 Ar[8];
    float  Br[16];

    auto loadA = [&](int t) {
        const float* p = aptr + t * KC;
        #pragma unroll
        for (int i = 0; i < 8; ++i)
            Ar[i] = *reinterpret_cast<const float4*>(p + (size_t)i * 16 * S_DIM);
    };
    auto loadB = [&](int t) {
        const float* bp = Bbase + (size_t)t * KC * D_DIM + bd;
        #pragma unroll
        for (int i = 0; i < 4; ++i)
            #pragma unroll
            for (int j = 0; j < 4; ++j)
                Br[i * 4 + j] = bp[(size_t)(bk0 + i * 32 + j) * D_DIM];
    };
    auto storeA = [&](ushort* la) {
        #pragma unroll
        for (int i = 0; i < 8; ++i) {
            short4_t v;
            v[0] = (short)f2bf(Ar[i].x); v[1] = (short)f2bf(Ar[i].y);
            v[2] = (short)f2bf(Ar[i].z); v[3] = (short)f2bf(Ar[i].w);
            *reinterpret_cast<short4_t*>(&la[aw_u16 + i * 16 * KC]) = v;
        }
    };
    auto storeB = [&](ushort* lb) {
        #pragma unroll
        for (int i = 0; i < 4; ++i) {
            short4_t v;
            #pragma unroll
            for (int j = 0; j < 4; ++j) v[j] = (short)f2bf(Br[i * 4 + j]);
            *reinterpret_cast<short4_t*>(&lb[bd * BSTRIDE + bk0 + i * 32]) = v;
        }
    };

    f32x4 acc[4];
    #pragma unroll
    for (int nf = 0; nf < 4; ++nf) acc[nf] = f32x4{0.f, 0.f, 0.f, 0.f};

    auto compute = [&](const ushort* la, const ushort* lb) {
        short8_t af[4];
        #pragma unroll
        for (int ks = 0; ks < 4; ++ks)
            af[ks] = *reinterpret_cast<const short8_t*>(&la[aidx[ks]]);
        #pragma unroll
        for (int ks = 0; ks < 4; ++ks)
            #pragma unroll
            for (int nf = 0; nf < 4; ++nf) {
                short8_t bf = *reinterpret_cast<const short8_t*>(&lb[bbase[nf] + ks * 32]);
                acc[nf] = __builtin_amdgcn_mfma_f32_16x16x32_bf16(
                    af[ks], bf, acc[nf], 0, 0, 0);
            }
    };

    // ---- pipeline: issue t+1 early, compute t, publish t+1, 1 barrier/chunk
    loadA(0); loadB(0);
    storeA(&lds_a[0][0]); storeB(&lds_b[0][0]);
    SYNC();

    #pragma unroll 1
    for (int t = 0; t < NCHUNK; ++t) {
        if (t + 1 < NCHUNK) { loadA(t + 1); loadB(t + 1); }
        __builtin_amdgcn_sched_barrier(0);   // loads issue before compute
        compute(&lds_a[t & 1][0], &lds_b[t & 1][0]);
        __builtin_amdgcn_sched_barrier(0);   // MFMAs stay above the vmcnt wait
        if (t + 1 < NCHUNK) {
            storeA(&lds_a[(t + 1) & 1][0]);
            storeB(&lds_b[(t + 1) & 1][0]);
            SYNC();
        }
    }

    // epilogue: C/D layout col = lane&15, row = (lane>>4)*4 + j  [m89-verified]
    #pragma unroll
    for (int nf = 0; nf < 4; ++nf)
        #pragma unroll
        for (int j = 0; j < 4; ++j) {
            const int r = w * 16 + fg * 4 + j;
            const int c = nf * 16 + fr;
            Cbase[(size_t)r * D_DIM + c] = acc[nf][j];
        }
}

extern "C" void kernel_launch(void* const* d_in, const int* in_sizes, int n_in,
                              void* d_out, int out_size, void* d_ws, size_t ws_size,
                              hipStream_t stream) {
    const float* x1 = (const float*)d_in[0];
    const float* x2 = (const float*)d_in[1];
    float* out = (float*)d_out;
    dim3 grid(256), block(THREADS);
    gemm_sm_kernel<<<grid, block, 0, stream>>>(x1, x2, out);
}